// Round 2
// baseline (1145.154 us; speedup 1.0000x reference)
//
#include <hip/hip_runtime.h>
#include <hip/hip_bf16.h>
#include <cmath>
#include <cstdint>

// Problem constants (from reference): N=100000, D=512, H1=16, C=40, NNZ=3.2M
#define DD 512
#define HH 16
#define CC 40
#define KC 32     // K-chunk for k_gemm1 LDS staging

#define BSH 7                 // log2 rows per bucket
#define BROWS (1 << BSH)      // 128 dest rows per bucket -> NB1 = 782 buckets
#define ACCP 17               // padded LDS acc stride (bank-spread for ds_add)
#define EPB 4096              // edges per block in hist/scatter (512 thr x 8)

// ---------------------------------------------------------------------------
// K1: X1 = H @ W1   (N x 512) @ (512 x 16) -> (N x 16)
// 128 threads / 128 rows per block; H staged via LDS coalesced; W1 via
// lane-invariant scalar loads.
// ---------------------------------------------------------------------------
__global__ __launch_bounds__(128) void k_gemm1(const float* __restrict__ Hm,
                                               const float* __restrict__ W1,
                                               float* __restrict__ X1,
                                               int nrows) {
    __shared__ float hs[128 * (KC + 1)];
    const int row = blockIdx.x * 128 + (int)threadIdx.x;

    float acc[HH];
#pragma unroll
    for (int j = 0; j < HH; ++j) acc[j] = 0.f;

    for (int kc = 0; kc < DD; kc += KC) {
        __syncthreads();
#pragma unroll
        for (int it = 0; it < (128 * KC / 4) / 128; ++it) {
            int f  = it * 128 + (int)threadIdx.x;
            int r  = f >> 3;
            int c4 = f & 7;
            int gr = blockIdx.x * 128 + r;
            float4 v = make_float4(0.f, 0.f, 0.f, 0.f);
            if (gr < nrows)
                v = *reinterpret_cast<const float4*>(&Hm[(size_t)gr * DD + kc + c4 * 4]);
            float* dst = &hs[r * (KC + 1) + c4 * 4];
            dst[0] = v.x; dst[1] = v.y; dst[2] = v.z; dst[3] = v.w;
        }
        __syncthreads();

        const float* hrow = &hs[threadIdx.x * (KC + 1)];
#pragma unroll
        for (int kk = 0; kk < KC; ++kk) {
            float h = hrow[kk];
            const float4* wr = reinterpret_cast<const float4*>(&W1[(kc + kk) * HH]);
            float4 w0 = wr[0], w1v = wr[1], w2v = wr[2], w3v = wr[3];
            acc[0]  += h * w0.x;  acc[1]  += h * w0.y;  acc[2]  += h * w0.z;  acc[3]  += h * w0.w;
            acc[4]  += h * w1v.x; acc[5]  += h * w1v.y; acc[6]  += h * w1v.z; acc[7]  += h * w1v.w;
            acc[8]  += h * w2v.x; acc[9]  += h * w2v.y; acc[10] += h * w2v.z; acc[11] += h * w2v.w;
            acc[12] += h * w3v.x; acc[13] += h * w3v.y; acc[14] += h * w3v.z; acc[15] += h * w3v.w;
        }
    }

    if (row < nrows) {
        float4* outp = reinterpret_cast<float4*>(&X1[(size_t)row * HH]);
#pragma unroll
        for (int j4 = 0; j4 < 4; ++j4)
            outp[j4] = make_float4(acc[j4 * 4 + 0], acc[j4 * 4 + 1],
                                   acc[j4 * 4 + 2], acc[j4 * 4 + 3]);
    }
}

// ---------------------------------------------------------------------------
// Bucket build: histogram (LDS-aggregated) -> 1-block scan -> scatter with
// per-block chunk reservation (contiguous per-bucket writes: no 8x write
// amplification, XCD-private write chunks).
// ---------------------------------------------------------------------------
__global__ __launch_bounds__(512) void k_bhist(const int* __restrict__ rows,
                                               int* __restrict__ bcnt,
                                               int nnz, int nb) {
    __shared__ int lh[1024];
    for (int i = (int)threadIdx.x; i < nb; i += 512) lh[i] = 0;
    __syncthreads();
    int base = blockIdx.x * EPB;
#pragma unroll
    for (int k = 0; k < EPB / 512; ++k) {
        int e = base + k * 512 + (int)threadIdx.x;
        if (e < nnz) atomicAdd(&lh[rows[e] >> BSH], 1);
    }
    __syncthreads();
    for (int i = (int)threadIdx.x; i < nb; i += 512) {
        int c = lh[i];
        if (c) atomicAdd(&bcnt[i], c);
    }
}

__global__ __launch_bounds__(1024) void k_bscan(const int* __restrict__ bcnt,
                                                int* __restrict__ bofs,
                                                int* __restrict__ bfill,
                                                int nb, int nnz) {
    __shared__ int sd[1024];
    int t = (int)threadIdx.x;
    int v = (t < nb) ? bcnt[t] : 0;
    sd[t] = v;
    __syncthreads();
    for (int off = 1; off < 1024; off <<= 1) {
        int x = (t >= off) ? sd[t - off] : 0;
        __syncthreads();
        sd[t] += x;
        __syncthreads();
    }
    if (t < nb) { bofs[t] = sd[t] - v; bfill[t] = 0; }
    if (t == 0) bofs[nb] = nnz;
}

__global__ __launch_bounds__(512) void k_bscatter(const int* __restrict__ rows,
                                                  const int* __restrict__ cols,
                                                  const float* __restrict__ vals,
                                                  const int* __restrict__ bofs,
                                                  int* __restrict__ bfill,
                                                  int2* __restrict__ pairs,
                                                  int nnz, int nb) {
    __shared__ int lh[1024];
    __shared__ int lb[1024];
    for (int i = (int)threadIdx.x; i < nb; i += 512) lh[i] = 0;
    __syncthreads();

    int base = blockIdx.x * EPB;
    int pk[EPB / 512], bk[EPB / 512], rk[EPB / 512];
    float vv[EPB / 512];
#pragma unroll
    for (int k = 0; k < EPB / 512; ++k) {
        int e = base + k * 512 + (int)threadIdx.x;
        bk[k] = -1;
        if (e < nnz) {
            int r = rows[e];
            int b = r >> BSH;
            bk[k] = b;
            pk[k] = cols[e] | ((r & (BROWS - 1)) << 20);
            vv[k] = vals[e];
            rk[k] = atomicAdd(&lh[b], 1);       // local rank within (block, bucket)
        }
    }
    __syncthreads();
    for (int i = (int)threadIdx.x; i < nb; i += 512) {
        int c = lh[i];
        lb[i] = c ? (bofs[i] + atomicAdd(&bfill[i], c)) : 0;  // reserve chunk
    }
    __syncthreads();
#pragma unroll
    for (int k = 0; k < EPB / 512; ++k) {
        if (bk[k] >= 0)
            pairs[(size_t)lb[bk[k]] + rk[k]] = make_int2(pk[k], __float_as_int(vv[k]));
    }
}

// ---------------------------------------------------------------------------
// Bucketed SpMM: one block per bucket of 128 dest rows. Stream the bucket's
// edges coalesced, gather X[col] (L3-resident), ds_add_f32 into a padded
// 128x16 LDS tile, then one coalesced write. Zero global f32 atomics.
// f = identity (layer 1) or relu(x + b1) (layer 2, fused).
// ---------------------------------------------------------------------------
template <int RELU_IN>
__global__ __launch_bounds__(256) void k_spmm_bucket(const int* __restrict__ bofs,
                                                     const int2* __restrict__ pairs,
                                                     const float* __restrict__ X,
                                                     float* __restrict__ S,
                                                     const float* __restrict__ bias,
                                                     int nrows) {
    __shared__ float acc[BROWS * ACCP];
    for (int i = (int)threadIdx.x; i < BROWS * ACCP; i += 256) acc[i] = 0.f;

    float4 b0, b1v, b2v, b3v;
    if (RELU_IN) {
        const float4* bp = reinterpret_cast<const float4*>(bias);
        b0 = bp[0]; b1v = bp[1]; b2v = bp[2]; b3v = bp[3];
    }
    __syncthreads();

    const int bb = blockIdx.x;
    const int s = bofs[bb], e = bofs[bb + 1];
    for (int k = s + (int)threadIdx.x; k < e; k += 256) {
        int2 p = pairs[k];
        int col = p.x & 0xFFFFF;
        int rl  = p.x >> 20;
        float v = __int_as_float(p.y);
        const float4* xp = reinterpret_cast<const float4*>(&X[(size_t)col * HH]);
        float4 x0 = xp[0], x1 = xp[1], x2 = xp[2], x3 = xp[3];
        if (RELU_IN) {
            x0.x = fmaxf(x0.x + b0.x, 0.f);  x0.y = fmaxf(x0.y + b0.y, 0.f);
            x0.z = fmaxf(x0.z + b0.z, 0.f);  x0.w = fmaxf(x0.w + b0.w, 0.f);
            x1.x = fmaxf(x1.x + b1v.x, 0.f); x1.y = fmaxf(x1.y + b1v.y, 0.f);
            x1.z = fmaxf(x1.z + b1v.z, 0.f); x1.w = fmaxf(x1.w + b1v.w, 0.f);
            x2.x = fmaxf(x2.x + b2v.x, 0.f); x2.y = fmaxf(x2.y + b2v.y, 0.f);
            x2.z = fmaxf(x2.z + b2v.z, 0.f); x2.w = fmaxf(x2.w + b2v.w, 0.f);
            x3.x = fmaxf(x3.x + b3v.x, 0.f); x3.y = fmaxf(x3.y + b3v.y, 0.f);
            x3.z = fmaxf(x3.z + b3v.z, 0.f); x3.w = fmaxf(x3.w + b3v.w, 0.f);
        }
        float* ar = &acc[rl * ACCP];
        atomicAdd(&ar[0],  v * x0.x); atomicAdd(&ar[1],  v * x0.y);
        atomicAdd(&ar[2],  v * x0.z); atomicAdd(&ar[3],  v * x0.w);
        atomicAdd(&ar[4],  v * x1.x); atomicAdd(&ar[5],  v * x1.y);
        atomicAdd(&ar[6],  v * x1.z); atomicAdd(&ar[7],  v * x1.w);
        atomicAdd(&ar[8],  v * x2.x); atomicAdd(&ar[9],  v * x2.y);
        atomicAdd(&ar[10], v * x2.z); atomicAdd(&ar[11], v * x2.w);
        atomicAdd(&ar[12], v * x3.x); atomicAdd(&ar[13], v * x3.y);
        atomicAdd(&ar[14], v * x3.z); atomicAdd(&ar[15], v * x3.w);
    }
    __syncthreads();

    const int rowbase = bb << BSH;
    for (int i = (int)threadIdx.x; i < BROWS * 4; i += 256) {
        int rl = i >> 2, sg = i & 3;
        int row = rowbase + rl;
        if (row < nrows) {
            const float* ap = &acc[rl * ACCP + sg * 4];
            *reinterpret_cast<float4*>(&S[(size_t)row * HH + sg * 4]) =
                make_float4(ap[0], ap[1], ap[2], ap[3]);
        }
    }
}

// ---------------------------------------------------------------------------
// Fallback scatter spmm (used only if workspace too small for bucket path).
// ---------------------------------------------------------------------------
__global__ __launch_bounds__(256) void k_spmm(const int* __restrict__ rows,
                                              const int* __restrict__ cols,
                                              const float* __restrict__ vals,
                                              const float* __restrict__ X,
                                              float* __restrict__ S,
                                              const float* __restrict__ bias,
                                              int relu_in, int nnz) {
    long long idx = (long long)blockIdx.x * 256 + threadIdx.x;
    if (idx >= (long long)nnz * HH) return;
    int e = (int)(idx >> 4);
    int j = (int)(idx & 15);
    int c = cols[e];
    int r = rows[e];
    float v = vals[e];
    float x = X[(size_t)c * HH + j];
    if (relu_in) {
        x = x + bias[j];
        x = x > 0.f ? x : 0.f;
    }
    atomicAdd(&S[(size_t)r * HH + j], v * x);
}

// ---------------------------------------------------------------------------
// K4: out = log_softmax(relu(T @ W2 + b2)).  One thread per row.
// ---------------------------------------------------------------------------
__global__ __launch_bounds__(256) void k_out(const float* __restrict__ T,
                                             const float* __restrict__ W2,
                                             const float* __restrict__ b2,
                                             float* __restrict__ out,
                                             int nrows) {
    __shared__ float w2s[HH * CC];
    __shared__ float b2s[CC];
    for (int i = (int)threadIdx.x; i < HH * CC; i += 256) w2s[i] = W2[i];
    if (threadIdx.x < CC) b2s[threadIdx.x] = b2[threadIdx.x];
    __syncthreads();

    int row = blockIdx.x * 256 + (int)threadIdx.x;
    if (row >= nrows) return;

    float t[HH];
#pragma unroll
    for (int k4 = 0; k4 < HH; k4 += 4) {
        float4 tv = *reinterpret_cast<const float4*>(&T[(size_t)row * HH + k4]);
        t[k4] = tv.x; t[k4 + 1] = tv.y; t[k4 + 2] = tv.z; t[k4 + 3] = tv.w;
    }

    float y[CC];
#pragma unroll
    for (int j = 0; j < CC; ++j) {
        float a = b2s[j];
#pragma unroll
        for (int k = 0; k < HH; ++k) a += t[k] * w2s[k * CC + j];
        y[j] = a > 0.f ? a : 0.f;
    }

    float m = y[0];
#pragma unroll
    for (int j = 1; j < CC; ++j) m = fmaxf(m, y[j]);
    float s = 0.f;
#pragma unroll
    for (int j = 0; j < CC; ++j) s += __expf(y[j] - m);
    float ls = __logf(s) + m;

    float4* op = reinterpret_cast<float4*>(&out[(size_t)row * CC]);
#pragma unroll
    for (int j4 = 0; j4 < CC / 4; ++j4)
        op[j4] = make_float4(y[j4 * 4 + 0] - ls, y[j4 * 4 + 1] - ls,
                             y[j4 * 4 + 2] - ls, y[j4 * 4 + 3] - ls);
}

// ---------------------------------------------------------------------------
// Inputs (setup_inputs order):
//  0: H      (N*512 f32)     1: A_vals (NNZ f32)   2: W1 (512*16 f32)
//  3: b1     (16 f32)        4: W2     (16*40 f32) 5: b2 (40 f32)
//  6: A_rows (NNZ i32)       7: A_cols (NNZ i32)
// Output: N*40 f32 (log_softmax)
// ---------------------------------------------------------------------------
extern "C" void kernel_launch(void* const* d_in, const int* in_sizes, int n_in,
                              void* d_out, int out_size, void* d_ws, size_t ws_size,
                              hipStream_t stream) {
    const float* Hm  = (const float*)d_in[0];
    const float* Av  = (const float*)d_in[1];
    const float* W1  = (const float*)d_in[2];
    const float* b1  = (const float*)d_in[3];
    const float* W2  = (const float*)d_in[4];
    const float* b2  = (const float*)d_in[5];
    const int*   Ar  = (const int*)d_in[6];
    const int*   Ac  = (const int*)d_in[7];
    float*       out = (float*)d_out;

    const int N   = in_sizes[0] / DD;
    const int NNZ = in_sizes[6];
    const int NB1 = (N + BROWS - 1) >> BSH;   // buckets of 128 dest rows

    // Workspace layout
    float* X1   = (float*)d_ws;                 // N*16
    float* S1   = X1 + (size_t)N * HH;          // N*16
    float* T    = S1 + (size_t)N * HH;          // N*16
    int*   bcnt = (int*)(T + (size_t)N * HH);   // NB1
    int*   bfil = bcnt + NB1;                   // NB1
    int*   bofs = bfil + NB1;                   // NB1+1
    int2*  pairs = (int2*)((((uintptr_t)(bofs + NB1 + 1)) + 7) & ~(uintptr_t)7);

    bool bucket_ok = (NB1 <= 1024) && (N < (1 << 20)) &&
                     (ws_size >= (size_t)((char*)(pairs + NNZ) - (char*)d_ws));

    // K1: X1 = H @ W1 (independent of bucket build)
    int g1 = (N + 127) / 128;
    k_gemm1<<<g1, 128, 0, stream>>>(Hm, W1, X1, N);

    if (bucket_ok) {
        hipMemsetAsync(bcnt, 0, (size_t)NB1 * sizeof(int), stream);
        int ge = (NNZ + EPB - 1) / EPB;
        k_bhist   <<<ge, 512, 0, stream>>>(Ar, bcnt, NNZ, NB1);
        k_bscan   <<<1, 1024, 0, stream>>>(bcnt, bofs, bfil, NB1, NNZ);
        k_bscatter<<<ge, 512, 0, stream>>>(Ar, Ac, Av, bofs, bfil, pairs, NNZ, NB1);

        // SpMM x2 (bucketed gather + LDS accumulate; no global f32 atomics)
        k_spmm_bucket<0><<<NB1, 256, 0, stream>>>(bofs, pairs, X1, S1, b1, N);
        k_spmm_bucket<1><<<NB1, 256, 0, stream>>>(bofs, pairs, S1, T,  b1, N);
    } else {
        hipMemsetAsync(S1, 0, (size_t)2 * N * HH * sizeof(float), stream);
        long long work = (long long)NNZ * HH;
        int g2 = (int)((work + 255) / 256);
        k_spmm<<<g2, 256, 0, stream>>>(Ar, Ac, Av, X1, S1, b1, 0, NNZ);
        k_spmm<<<g2, 256, 0, stream>>>(Ar, Ac, Av, S1, T,  b1, 1, NNZ);
    }

    // K4: out = log_softmax(relu(T @ W2 + b2))
    int g4 = (N + 255) / 256;
    k_out<<<g4, 256, 0, stream>>>(T, W2, b2, out, N);
}

// Round 3
// 1020.187 us; speedup vs baseline: 1.1225x; 1.1225x over previous
//
#include <hip/hip_runtime.h>
#include <hip/hip_bf16.h>
#include <cmath>
#include <cstdint>

// Problem constants (from reference): N=100000, D=512, H1=16, C=40, NNZ=3.2M
#define DD 512
#define HH 16
#define CC 40
#define KC 32     // K-chunk for k_gemm1 LDS staging

#define BSH 7                 // log2 rows per bucket
#define BROWS (1 << BSH)      // 128 dest rows per bucket -> NB1 = 782 buckets
#define ACCP 17               // padded LDS acc stride (bank-spread for ds_add)
#define EPB 4096              // edges per block in hist/scatter (512 thr x 8)
#define SPLIT 4               // blocks per bucket in spmm (occupancy + MLP)

// ---------------------------------------------------------------------------
// K1: X1 = H @ W1   (N x 512) @ (512 x 16) -> (N x 16)
// ---------------------------------------------------------------------------
__global__ __launch_bounds__(128) void k_gemm1(const float* __restrict__ Hm,
                                               const float* __restrict__ W1,
                                               float* __restrict__ X1,
                                               int nrows) {
    __shared__ float hs[128 * (KC + 1)];
    const int row = blockIdx.x * 128 + (int)threadIdx.x;

    float acc[HH];
#pragma unroll
    for (int j = 0; j < HH; ++j) acc[j] = 0.f;

    for (int kc = 0; kc < DD; kc += KC) {
        __syncthreads();
#pragma unroll
        for (int it = 0; it < (128 * KC / 4) / 128; ++it) {
            int f  = it * 128 + (int)threadIdx.x;
            int r  = f >> 3;
            int c4 = f & 7;
            int gr = blockIdx.x * 128 + r;
            float4 v = make_float4(0.f, 0.f, 0.f, 0.f);
            if (gr < nrows)
                v = *reinterpret_cast<const float4*>(&Hm[(size_t)gr * DD + kc + c4 * 4]);
            float* dst = &hs[r * (KC + 1) + c4 * 4];
            dst[0] = v.x; dst[1] = v.y; dst[2] = v.z; dst[3] = v.w;
        }
        __syncthreads();

        const float* hrow = &hs[threadIdx.x * (KC + 1)];
#pragma unroll
        for (int kk = 0; kk < KC; ++kk) {
            float h = hrow[kk];
            const float4* wr = reinterpret_cast<const float4*>(&W1[(kc + kk) * HH]);
            float4 w0 = wr[0], w1v = wr[1], w2v = wr[2], w3v = wr[3];
            acc[0]  += h * w0.x;  acc[1]  += h * w0.y;  acc[2]  += h * w0.z;  acc[3]  += h * w0.w;
            acc[4]  += h * w1v.x; acc[5]  += h * w1v.y; acc[6]  += h * w1v.z; acc[7]  += h * w1v.w;
            acc[8]  += h * w2v.x; acc[9]  += h * w2v.y; acc[10] += h * w2v.z; acc[11] += h * w2v.w;
            acc[12] += h * w3v.x; acc[13] += h * w3v.y; acc[14] += h * w3v.z; acc[15] += h * w3v.w;
        }
    }

    if (row < nrows) {
        float4* outp = reinterpret_cast<float4*>(&X1[(size_t)row * HH]);
#pragma unroll
        for (int j4 = 0; j4 < 4; ++j4)
            outp[j4] = make_float4(acc[j4 * 4 + 0], acc[j4 * 4 + 1],
                                   acc[j4 * 4 + 2], acc[j4 * 4 + 3]);
    }
}

// ---------------------------------------------------------------------------
// Bucket build, fully atomic-free:
//   k_bhist:   per-block LDS histogram -> row of cnt2D[NBLK][NB1]
//   k_colscan: per-bucket exclusive scan over blocks (column of cnt2D),
//              bucket totals -> bcnt
//   k_bscan:   exclusive scan of bucket totals -> bofs
//   k_bscatter:slot = bofs[b] + cnt2D[blk][b] + LDS-rank; contiguous chunks.
// ---------------------------------------------------------------------------
__global__ __launch_bounds__(512) void k_bhist(const int* __restrict__ rows,
                                               int* __restrict__ cnt2d,
                                               int nnz, int nb) {
    __shared__ int lh[1024];
    for (int i = (int)threadIdx.x; i < nb; i += 512) lh[i] = 0;
    __syncthreads();
    int base = blockIdx.x * EPB;
#pragma unroll
    for (int k = 0; k < EPB / 512; ++k) {
        int e = base + k * 512 + (int)threadIdx.x;
        if (e < nnz) atomicAdd(&lh[rows[e] >> BSH], 1);
    }
    __syncthreads();
    int* myrow = cnt2d + (size_t)blockIdx.x * nb;
    for (int i = (int)threadIdx.x; i < nb; i += 512) myrow[i] = lh[i];
}

__global__ __launch_bounds__(1024) void k_colscan(int* __restrict__ cnt2d,
                                                  int* __restrict__ bcnt,
                                                  int nblk, int nb) {
    __shared__ int sd[1024];
    int b = blockIdx.x;
    int t = (int)threadIdx.x;
    int v = (t < nblk) ? cnt2d[(size_t)t * nb + b] : 0;
    sd[t] = v;
    __syncthreads();
    for (int off = 1; off < 1024; off <<= 1) {
        int x = (t >= off) ? sd[t - off] : 0;
        __syncthreads();
        sd[t] += x;
        __syncthreads();
    }
    if (t < nblk) cnt2d[(size_t)t * nb + b] = sd[t] - v;  // exclusive over blocks
    if (t == 1023) bcnt[b] = sd[1023];                    // bucket total
}

__global__ __launch_bounds__(1024) void k_bscan(const int* __restrict__ bcnt,
                                                int* __restrict__ bofs,
                                                int nb, int nnz) {
    __shared__ int sd[1024];
    int t = (int)threadIdx.x;
    int v = (t < nb) ? bcnt[t] : 0;
    sd[t] = v;
    __syncthreads();
    for (int off = 1; off < 1024; off <<= 1) {
        int x = (t >= off) ? sd[t - off] : 0;
        __syncthreads();
        sd[t] += x;
        __syncthreads();
    }
    if (t < nb) bofs[t] = sd[t] - v;
    if (t == 0) bofs[nb] = nnz;
}

__global__ __launch_bounds__(512) void k_bscatter(const int* __restrict__ rows,
                                                  const int* __restrict__ cols,
                                                  const float* __restrict__ vals,
                                                  const int* __restrict__ bofs,
                                                  const int* __restrict__ cnt2d,
                                                  int2* __restrict__ pairs,
                                                  int nnz, int nb) {
    __shared__ int lh[1024];
    __shared__ int lb[1024];
    for (int i = (int)threadIdx.x; i < nb; i += 512) lh[i] = 0;
    __syncthreads();

    int base = blockIdx.x * EPB;
    int pk[EPB / 512], bk[EPB / 512], rk[EPB / 512];
    float vv[EPB / 512];
#pragma unroll
    for (int k = 0; k < EPB / 512; ++k) {
        int e = base + k * 512 + (int)threadIdx.x;
        bk[k] = -1;
        if (e < nnz) {
            int r = rows[e];
            int b = r >> BSH;
            bk[k] = b;
            pk[k] = cols[e] | ((r & (BROWS - 1)) << 20);
            vv[k] = vals[e];
            rk[k] = atomicAdd(&lh[b], 1);       // LDS rank within (block, bucket)
        }
    }
    __syncthreads();
    const int* myrow = cnt2d + (size_t)blockIdx.x * nb;
    for (int i = (int)threadIdx.x; i < nb; i += 512)
        lb[i] = bofs[i] + myrow[i];             // precomputed base: no atomics
    __syncthreads();
#pragma unroll
    for (int k = 0; k < EPB / 512; ++k) {
        if (bk[k] >= 0)
            pairs[(size_t)lb[bk[k]] + rk[k]] = make_int2(pk[k], __float_as_int(vv[k]));
    }
}

// ---------------------------------------------------------------------------
// Bucketed SpMM v2: SPLIT blocks per bucket of 128 dest rows. Edge loop
// unrolled x4 with batched gathers (4 x 64B in flight per lane). Private LDS
// tile per block, merged with coalesced global atomicAdd (4-way contention).
// ---------------------------------------------------------------------------
template <int RELU_IN>
__global__ __launch_bounds__(256) void k_spmm_bucket(const int* __restrict__ bofs,
                                                     const int2* __restrict__ pairs,
                                                     const float* __restrict__ X,
                                                     float* __restrict__ S,
                                                     const float* __restrict__ bias,
                                                     int nrows) {
    const int bb  = blockIdx.x / SPLIT;
    const int sub = blockIdx.x % SPLIT;
    const int s = bofs[bb], e = bofs[bb + 1];
    if (s + sub * 256 >= e) return;     // uniform: empty sub-range

    __shared__ float acc[BROWS * ACCP];
    for (int i = (int)threadIdx.x; i < BROWS * ACCP; i += 256) acc[i] = 0.f;

    float4 bv[4];
    if (RELU_IN) {
        const float4* bp = reinterpret_cast<const float4*>(bias);
#pragma unroll
        for (int q = 0; q < 4; ++q) bv[q] = bp[q];
    }
    __syncthreads();

    const int STR = 256 * SPLIT;
    int k = s + sub * 256 + (int)threadIdx.x;

    // main: 4 edges in flight per lane
    for (; k + 3 * STR < e; k += 4 * STR) {
        int2 p[4];
        p[0] = pairs[k];
        p[1] = pairs[k + STR];
        p[2] = pairs[k + 2 * STR];
        p[3] = pairs[k + 3 * STR];
        float4 xv[4][4];
#pragma unroll
        for (int u = 0; u < 4; ++u) {
            const float4* xp = reinterpret_cast<const float4*>(&X[(size_t)(p[u].x & 0xFFFFF) * HH]);
            xv[u][0] = xp[0]; xv[u][1] = xp[1]; xv[u][2] = xp[2]; xv[u][3] = xp[3];
        }
#pragma unroll
        for (int u = 0; u < 4; ++u) {
            float v = __int_as_float(p[u].y);
            float* ar = &acc[(p[u].x >> 20) * ACCP];
#pragma unroll
            for (int q = 0; q < 4; ++q) {
                float4 x = xv[u][q];
                if (RELU_IN) {
                    x.x = fmaxf(x.x + bv[q].x, 0.f); x.y = fmaxf(x.y + bv[q].y, 0.f);
                    x.z = fmaxf(x.z + bv[q].z, 0.f); x.w = fmaxf(x.w + bv[q].w, 0.f);
                }
                atomicAdd(&ar[q * 4 + 0], v * x.x);
                atomicAdd(&ar[q * 4 + 1], v * x.y);
                atomicAdd(&ar[q * 4 + 2], v * x.z);
                atomicAdd(&ar[q * 4 + 3], v * x.w);
            }
        }
    }
    // remainder
    for (; k < e; k += STR) {
        int2 p = pairs[k];
        float v = __int_as_float(p.y);
        const float4* xp = reinterpret_cast<const float4*>(&X[(size_t)(p.x & 0xFFFFF) * HH]);
        float* ar = &acc[(p.x >> 20) * ACCP];
#pragma unroll
        for (int q = 0; q < 4; ++q) {
            float4 x = xp[q];
            if (RELU_IN) {
                x.x = fmaxf(x.x + bv[q].x, 0.f); x.y = fmaxf(x.y + bv[q].y, 0.f);
                x.z = fmaxf(x.z + bv[q].z, 0.f); x.w = fmaxf(x.w + bv[q].w, 0.f);
            }
            atomicAdd(&ar[q * 4 + 0], v * x.x);
            atomicAdd(&ar[q * 4 + 1], v * x.y);
            atomicAdd(&ar[q * 4 + 2], v * x.z);
            atomicAdd(&ar[q * 4 + 3], v * x.w);
        }
    }
    __syncthreads();

    // merge private tile into S (coalesced; <=SPLIT-way contention per addr)
    const int rowbase = bb << BSH;
    for (int i = (int)threadIdx.x; i < BROWS * HH; i += 256) {
        int rl = i >> 4, j = i & 15;
        int row = rowbase + rl;
        if (row < nrows) {
            float vsum = acc[rl * ACCP + j];
            if (vsum != 0.f) atomicAdd(&S[(size_t)row * HH + j], vsum);
        }
    }
}

// ---------------------------------------------------------------------------
// Fallback scatter spmm (used only if workspace too small for bucket path).
// ---------------------------------------------------------------------------
__global__ __launch_bounds__(256) void k_spmm(const int* __restrict__ rows,
                                              const int* __restrict__ cols,
                                              const float* __restrict__ vals,
                                              const float* __restrict__ X,
                                              float* __restrict__ S,
                                              const float* __restrict__ bias,
                                              int relu_in, int nnz) {
    long long idx = (long long)blockIdx.x * 256 + threadIdx.x;
    if (idx >= (long long)nnz * HH) return;
    int e = (int)(idx >> 4);
    int j = (int)(idx & 15);
    int c = cols[e];
    int r = rows[e];
    float v = vals[e];
    float x = X[(size_t)c * HH + j];
    if (relu_in) {
        x = x + bias[j];
        x = x > 0.f ? x : 0.f;
    }
    atomicAdd(&S[(size_t)r * HH + j], v * x);
}

// ---------------------------------------------------------------------------
// K4: out = log_softmax(relu(T @ W2 + b2)).  One thread per row.
// ---------------------------------------------------------------------------
__global__ __launch_bounds__(256) void k_out(const float* __restrict__ T,
                                             const float* __restrict__ W2,
                                             const float* __restrict__ b2,
                                             float* __restrict__ out,
                                             int nrows) {
    __shared__ float w2s[HH * CC];
    __shared__ float b2s[CC];
    for (int i = (int)threadIdx.x; i < HH * CC; i += 256) w2s[i] = W2[i];
    if (threadIdx.x < CC) b2s[threadIdx.x] = b2[threadIdx.x];
    __syncthreads();

    int row = blockIdx.x * 256 + (int)threadIdx.x;
    if (row >= nrows) return;

    float t[HH];
#pragma unroll
    for (int k4 = 0; k4 < HH; k4 += 4) {
        float4 tv = *reinterpret_cast<const float4*>(&T[(size_t)row * HH + k4]);
        t[k4] = tv.x; t[k4 + 1] = tv.y; t[k4 + 2] = tv.z; t[k4 + 3] = tv.w;
    }

    float y[CC];
#pragma unroll
    for (int j = 0; j < CC; ++j) {
        float a = b2s[j];
#pragma unroll
        for (int k = 0; k < HH; ++k) a += t[k] * w2s[k * CC + j];
        y[j] = a > 0.f ? a : 0.f;
    }

    float m = y[0];
#pragma unroll
    for (int j = 1; j < CC; ++j) m = fmaxf(m, y[j]);
    float s = 0.f;
#pragma unroll
    for (int j = 0; j < CC; ++j) s += __expf(y[j] - m);
    float ls = __logf(s) + m;

    float4* op = reinterpret_cast<float4*>(&out[(size_t)row * CC]);
#pragma unroll
    for (int j4 = 0; j4 < CC / 4; ++j4)
        op[j4] = make_float4(y[j4 * 4 + 0] - ls, y[j4 * 4 + 1] - ls,
                             y[j4 * 4 + 2] - ls, y[j4 * 4 + 3] - ls);
}

// ---------------------------------------------------------------------------
// Inputs (setup_inputs order):
//  0: H      (N*512 f32)     1: A_vals (NNZ f32)   2: W1 (512*16 f32)
//  3: b1     (16 f32)        4: W2     (16*40 f32) 5: b2 (40 f32)
//  6: A_rows (NNZ i32)       7: A_cols (NNZ i32)
// Output: N*40 f32 (log_softmax)
// ---------------------------------------------------------------------------
extern "C" void kernel_launch(void* const* d_in, const int* in_sizes, int n_in,
                              void* d_out, int out_size, void* d_ws, size_t ws_size,
                              hipStream_t stream) {
    const float* Hm  = (const float*)d_in[0];
    const float* Av  = (const float*)d_in[1];
    const float* W1  = (const float*)d_in[2];
    const float* b1  = (const float*)d_in[3];
    const float* W2  = (const float*)d_in[4];
    const float* b2  = (const float*)d_in[5];
    const int*   Ar  = (const int*)d_in[6];
    const int*   Ac  = (const int*)d_in[7];
    float*       out = (float*)d_out;

    const int N    = in_sizes[0] / DD;
    const int NNZ  = in_sizes[6];
    const int NB1  = (N + BROWS - 1) >> BSH;       // buckets of 128 dest rows
    const int NBLK = (NNZ + EPB - 1) / EPB;        // edge blocks

    // Workspace layout
    float* X1    = (float*)d_ws;                   // N*16
    float* S1    = X1 + (size_t)N * HH;            // N*16
    float* T     = S1 + (size_t)N * HH;            // N*16
    int*   bcnt  = (int*)(T + (size_t)N * HH);     // NB1
    int*   bofs  = bcnt + NB1;                     // NB1+1
    int*   cnt2d = bofs + NB1 + 1;                 // NBLK*NB1
    int2*  pairs = (int2*)((((uintptr_t)(cnt2d + (size_t)NBLK * NB1)) + 7) & ~(uintptr_t)7);

    bool bucket_ok = (NB1 <= 1024) && (NBLK <= 1024) && (N < (1 << 20)) &&
                     (ws_size >= (size_t)((char*)(pairs + NNZ) - (char*)d_ws));

    // K1: X1 = H @ W1 (independent of bucket build)
    int g1 = (N + 127) / 128;
    k_gemm1<<<g1, 128, 0, stream>>>(Hm, W1, X1, N);

    if (bucket_ok) {
        // zero accumulators (S1, T adjacent)
        hipMemsetAsync(S1, 0, (size_t)2 * N * HH * sizeof(float), stream);

        // Atomic-free bucket build
        k_bhist   <<<NBLK, 512, 0, stream>>>(Ar, cnt2d, NNZ, NB1);
        k_colscan <<<NB1, 1024, 0, stream>>>(cnt2d, bcnt, NBLK, NB1);
        k_bscan   <<<1, 1024, 0, stream>>>(bcnt, bofs, NB1, NNZ);
        k_bscatter<<<NBLK, 512, 0, stream>>>(Ar, Ac, Av, bofs, cnt2d, pairs, NNZ, NB1);

        // SpMM x2 (bucketed gather, x4 MLP, LDS accumulate + coalesced merge)
        int gs = NB1 * SPLIT;
        k_spmm_bucket<0><<<gs, 256, 0, stream>>>(bofs, pairs, X1, S1, b1, N);
        k_spmm_bucket<1><<<gs, 256, 0, stream>>>(bofs, pairs, S1, T,  b1, N);
    } else {
        hipMemsetAsync(S1, 0, (size_t)2 * N * HH * sizeof(float), stream);
        long long work = (long long)NNZ * HH;
        int g2 = (int)((work + 255) / 256);
        k_spmm<<<g2, 256, 0, stream>>>(Ar, Ac, Av, X1, S1, b1, 0, NNZ);
        k_spmm<<<g2, 256, 0, stream>>>(Ar, Ac, Av, S1, T,  b1, 1, NNZ);
    }

    // K4: out = log_softmax(relu(T @ W2 + b2))
    int g4 = (N + 255) / 256;
    k_out<<<g4, 256, 0, stream>>>(T, W2, b2, out, N);
}

// Round 4
// 573.258 us; speedup vs baseline: 1.9976x; 1.7796x over previous
//
#include <hip/hip_runtime.h>
#include <hip/hip_bf16.h>
#include <cmath>
#include <cstdint>

// Problem constants (from reference): N=100000, D=512, H1=16, C=40, NNZ=3.2M
#define DD 512
#define HH 16
#define CC 40
#define KC 32     // K-chunk for k_gemm1 LDS staging
#define G1R 256   // rows per block in k_gemm1

#define BSH 7                 // log2 rows per bucket
#define BROWS (1 << BSH)      // 128 dest rows per bucket -> NB1 = 782 buckets
#define ACCP 17               // padded LDS acc stride (solo fallback)
#define EPB 4096              // edges per block in hist/scatter (512 thr x 8)
#define LCAP 5120             // max bucket edges for LDS sort (mean 4092, +16 sigma)

// ---------------------------------------------------------------------------
// K1: X1 = H @ W1   (N x 512) @ (512 x 16) -> (N x 16)
// 256 rows/block, H staged in XOR-quad-swizzled LDS (conflict-free b128
// reads/writes), W1 via lane-invariant global reads (-> scalar s_load, K$).
// ---------------------------------------------------------------------------
__global__ __launch_bounds__(256) void k_gemm1(const float* __restrict__ Hm,
                                               const float* __restrict__ W1,
                                               float* __restrict__ X1,
                                               int nrows) {
    __shared__ float hs[G1R * KC];   // 32 KB, quad-swizzled: quad q of row r at q^(r&7)
    const int tid = (int)threadIdx.x;
    const int row = blockIdx.x * G1R + tid;

    float acc[HH];
#pragma unroll
    for (int j = 0; j < HH; ++j) acc[j] = 0.f;

    for (int kc = 0; kc < DD; kc += KC) {
        __syncthreads();
        // stage 256 rows x 8 quads (coalesced 128B per 8 lanes)
#pragma unroll
        for (int it = 0; it < 8; ++it) {
            int f  = it * 256 + tid;
            int r  = f >> 3;
            int c4 = f & 7;
            int gr = blockIdx.x * G1R + r;
            float4 v = make_float4(0.f, 0.f, 0.f, 0.f);
            if (gr < nrows)
                v = *reinterpret_cast<const float4*>(&Hm[(size_t)gr * DD + kc + c4 * 4]);
            *reinterpret_cast<float4*>(&hs[r * KC + ((c4 ^ (r & 7)) << 2)]) = v;
        }
        __syncthreads();

        // own row's 8 quads via swizzled b128 (uniform bank spread)
        float4 h[8];
#pragma unroll
        for (int q = 0; q < 8; ++q)
            h[q] = *reinterpret_cast<const float4*>(&hs[tid * KC + ((q ^ (tid & 7)) << 2)]);

#pragma unroll
        for (int q = 0; q < 8; ++q) {
            float hv[4] = {h[q].x, h[q].y, h[q].z, h[q].w};
#pragma unroll
            for (int kk = 0; kk < 4; ++kk) {
                const float4* wr = reinterpret_cast<const float4*>(&W1[(kc + q * 4 + kk) * HH]);
                float4 w0 = wr[0], w1v = wr[1], w2v = wr[2], w3v = wr[3];
                float hx = hv[kk];
                acc[0]  += hx * w0.x;  acc[1]  += hx * w0.y;  acc[2]  += hx * w0.z;  acc[3]  += hx * w0.w;
                acc[4]  += hx * w1v.x; acc[5]  += hx * w1v.y; acc[6]  += hx * w1v.z; acc[7]  += hx * w1v.w;
                acc[8]  += hx * w2v.x; acc[9]  += hx * w2v.y; acc[10] += hx * w2v.z; acc[11] += hx * w2v.w;
                acc[12] += hx * w3v.x; acc[13] += hx * w3v.y; acc[14] += hx * w3v.z; acc[15] += hx * w3v.w;
            }
        }
    }

    if (row < nrows) {
        float4* outp = reinterpret_cast<float4*>(&X1[(size_t)row * HH]);
#pragma unroll
        for (int j4 = 0; j4 < 4; ++j4)
            outp[j4] = make_float4(acc[j4 * 4 + 0], acc[j4 * 4 + 1],
                                   acc[j4 * 4 + 2], acc[j4 * 4 + 3]);
    }
}

// ---------------------------------------------------------------------------
// Bucket build (atomic-free): bhist -> colscan -> bscan -> bscatter.
// ---------------------------------------------------------------------------
__global__ __launch_bounds__(512) void k_bhist(const int* __restrict__ rows,
                                               int* __restrict__ cnt2d,
                                               int nnz, int nb) {
    __shared__ int lh[1024];
    for (int i = (int)threadIdx.x; i < nb; i += 512) lh[i] = 0;
    __syncthreads();
    int base = blockIdx.x * EPB;
#pragma unroll
    for (int k = 0; k < EPB / 512; ++k) {
        int e = base + k * 512 + (int)threadIdx.x;
        if (e < nnz) atomicAdd(&lh[rows[e] >> BSH], 1);
    }
    __syncthreads();
    int* myrow = cnt2d + (size_t)blockIdx.x * nb;
    for (int i = (int)threadIdx.x; i < nb; i += 512) myrow[i] = lh[i];
}

__global__ __launch_bounds__(1024) void k_colscan(int* __restrict__ cnt2d,
                                                  int* __restrict__ bcnt,
                                                  int nblk, int nb) {
    __shared__ int sd[1024];
    int b = blockIdx.x;
    int t = (int)threadIdx.x;
    int v = (t < nblk) ? cnt2d[(size_t)t * nb + b] : 0;
    sd[t] = v;
    __syncthreads();
    for (int off = 1; off < 1024; off <<= 1) {
        int x = (t >= off) ? sd[t - off] : 0;
        __syncthreads();
        sd[t] += x;
        __syncthreads();
    }
    if (t < nblk) cnt2d[(size_t)t * nb + b] = sd[t] - v;  // exclusive over blocks
    if (t == 1023) bcnt[b] = sd[1023];                    // bucket total
}

__global__ __launch_bounds__(1024) void k_bscan(const int* __restrict__ bcnt,
                                                int* __restrict__ bofs,
                                                int nb, int nnz) {
    __shared__ int sd[1024];
    int t = (int)threadIdx.x;
    int v = (t < nb) ? bcnt[t] : 0;
    sd[t] = v;
    __syncthreads();
    for (int off = 1; off < 1024; off <<= 1) {
        int x = (t >= off) ? sd[t - off] : 0;
        __syncthreads();
        sd[t] += x;
        __syncthreads();
    }
    if (t < nb) bofs[t] = sd[t] - v;
    if (t == 0) bofs[nb] = nnz;
}

__global__ __launch_bounds__(512) void k_bscatter(const int* __restrict__ rows,
                                                  const int* __restrict__ cols,
                                                  const float* __restrict__ vals,
                                                  const int* __restrict__ bofs,
                                                  const int* __restrict__ cnt2d,
                                                  int2* __restrict__ pairs,
                                                  int nnz, int nb) {
    __shared__ int lh[1024];
    __shared__ int lb[1024];
    for (int i = (int)threadIdx.x; i < nb; i += 512) lh[i] = 0;
    __syncthreads();

    int base = blockIdx.x * EPB;
    int pk[EPB / 512], bk[EPB / 512], rk[EPB / 512];
    float vv[EPB / 512];
#pragma unroll
    for (int k = 0; k < EPB / 512; ++k) {
        int e = base + k * 512 + (int)threadIdx.x;
        bk[k] = -1;
        if (e < nnz) {
            int r = rows[e];
            int b = r >> BSH;
            bk[k] = b;
            pk[k] = cols[e] | ((r & (BROWS - 1)) << 20);
            vv[k] = vals[e];
            rk[k] = atomicAdd(&lh[b], 1);       // LDS rank within (block, bucket)
        }
    }
    __syncthreads();
    const int* myrow = cnt2d + (size_t)blockIdx.x * nb;
    for (int i = (int)threadIdx.x; i < nb; i += 512)
        lb[i] = bofs[i] + myrow[i];             // precomputed base: no atomics
    __syncthreads();
#pragma unroll
    for (int k = 0; k < EPB / 512; ++k) {
        if (bk[k] >= 0)
            pairs[(size_t)lb[bk[k]] + rk[k]] = make_int2(pk[k], __float_as_int(vv[k]));
    }
}

// ---------------------------------------------------------------------------
// k_bsort: per-bucket counting sort (LDS-staged, in-place) -> full CSR rofs.
// 2 LDS atomics/edge total (vs 16 ds_add/edge before). Strips rl from col.
// Oversized bucket (practically impossible): flag + degenerate rofs, handled
// by k_spmm_solo afterwards.
// ---------------------------------------------------------------------------
__global__ __launch_bounds__(256) void k_bsort(const int* __restrict__ bofs,
                                               int2* __restrict__ pairs,
                                               int* __restrict__ rofs,
                                               int* __restrict__ bflag,
                                               int nrows) {
    __shared__ int2 lp[LCAP];
    __shared__ int  cnt[BROWS];
    __shared__ int  base[BROWS + 1];
    const int b = blockIdx.x, t = (int)threadIdx.x;
    const int s = bofs[b], e = bofs[b + 1], n = e - s;
    const int rowbase = b << BSH;

    if (n > LCAP) {             // degenerate path; k_spmm_solo owns these rows
        if (t == 0) bflag[b] = 1;
        for (int i = t; i < BROWS; i += 256) {
            int row = rowbase + i;
            if (row <= nrows) rofs[row] = s;
        }
        return;
    }
    if (t == 0) bflag[b] = 0;

    for (int i = t; i < BROWS; i += 256) cnt[i] = 0;
    for (int i = t; i < n; i += 256) lp[i] = pairs[s + i];
    __syncthreads();
    for (int i = t; i < n; i += 256) atomicAdd(&cnt[lp[i].x >> 20], 1);
    __syncthreads();

    // exclusive scan of 128 counters
    int own = (t < BROWS) ? cnt[t] : 0;
    if (t < BROWS) base[t] = own;
    __syncthreads();
    for (int off = 1; off < BROWS; off <<= 1) {
        int x = (t < BROWS && t >= off) ? base[t - off] : 0;
        __syncthreads();
        if (t < BROWS) base[t] += x;
        __syncthreads();
    }
    if (t < BROWS) base[t] -= own;              // own-element only: race-free
    if (t == 0) base[BROWS] = n;
    for (int i = t; i < BROWS; i += 256) cnt[i] = 0;   // reuse as rank counters
    __syncthreads();

    // CSR row offsets (i==BROWS double-written by next bucket with same value)
    for (int i = t; i < BROWS + 1; i += 256) {
        int row = rowbase + i;
        if (row <= nrows) rofs[row] = s + base[i];
    }
    // in-place scatter, strip rl
    for (int i = t; i < n; i += 256) {
        int2 p = lp[i];
        int rl = p.x >> 20;
        int r  = atomicAdd(&cnt[rl], 1);
        pairs[s + base[rl] + r] = make_int2(p.x & 0xFFFFF, p.y);
    }
}

// ---------------------------------------------------------------------------
// Row-gather SpMM: zero atomics. 4 lanes per row, each owns a float4 of the
// 16 features; 4 edges in flight per lane (4 independent 16B gathers).
// f = identity (layer 1) or relu(x + b1) (layer 2, fused).
// ---------------------------------------------------------------------------
template <int RELU_IN>
__global__ __launch_bounds__(256) void k_spmm_row(const int* __restrict__ rofs,
                                                  const int2* __restrict__ pairs,
                                                  const float* __restrict__ X,
                                                  float* __restrict__ S,
                                                  const float* __restrict__ bias,
                                                  int nrows) {
    const int g = blockIdx.x * 64 + ((int)threadIdx.x >> 2);
    if (g >= nrows) return;
    const int lj = ((int)threadIdx.x & 3) * 4;
    const int s = rofs[g], e = rofs[g + 1];

    float4 bq = make_float4(0.f, 0.f, 0.f, 0.f);
    if (RELU_IN) bq = *reinterpret_cast<const float4*>(&bias[lj]);

    float a0 = 0.f, a1 = 0.f, a2 = 0.f, a3 = 0.f;
#define ACC1(P, XV)                                                        \
    {                                                                      \
        float v_ = __int_as_float((P).y);                                  \
        float4 x_ = (XV);                                                  \
        if (RELU_IN) {                                                     \
            x_.x = fmaxf(x_.x + bq.x, 0.f); x_.y = fmaxf(x_.y + bq.y, 0.f);\
            x_.z = fmaxf(x_.z + bq.z, 0.f); x_.w = fmaxf(x_.w + bq.w, 0.f);\
        }                                                                  \
        a0 += v_ * x_.x; a1 += v_ * x_.y; a2 += v_ * x_.z; a3 += v_ * x_.w;\
    }

    int k = s;
    for (; k + 4 <= e; k += 4) {
        int2 p0 = pairs[k], p1 = pairs[k + 1], p2 = pairs[k + 2], p3 = pairs[k + 3];
        float4 x0 = *reinterpret_cast<const float4*>(&X[(size_t)p0.x * HH + lj]);
        float4 x1 = *reinterpret_cast<const float4*>(&X[(size_t)p1.x * HH + lj]);
        float4 x2 = *reinterpret_cast<const float4*>(&X[(size_t)p2.x * HH + lj]);
        float4 x3 = *reinterpret_cast<const float4*>(&X[(size_t)p3.x * HH + lj]);
        ACC1(p0, x0) ACC1(p1, x1) ACC1(p2, x2) ACC1(p3, x3)
    }
    for (; k < e; ++k) {
        int2 p = pairs[k];
        float4 x = *reinterpret_cast<const float4*>(&X[(size_t)p.x * HH + lj]);
        ACC1(p, x)
    }
#undef ACC1

    *reinterpret_cast<float4*>(&S[(size_t)g * HH + lj]) = make_float4(a0, a1, a2, a3);
}

// ---------------------------------------------------------------------------
// Insurance: single-block bucket accumulate for oversized (unsorted) buckets.
// No-op when all bflag==0 (the practical case).
// ---------------------------------------------------------------------------
template <int RELU_IN>
__global__ __launch_bounds__(256) void k_spmm_solo(const int* __restrict__ bofs,
                                                   const int* __restrict__ bflag,
                                                   const int2* __restrict__ pairs,
                                                   const float* __restrict__ X,
                                                   float* __restrict__ S,
                                                   const float* __restrict__ bias,
                                                   int nrows) {
    const int b = blockIdx.x;
    if (bflag[b] == 0) return;
    __shared__ float acc[BROWS * ACCP];
    for (int i = (int)threadIdx.x; i < BROWS * ACCP; i += 256) acc[i] = 0.f;
    float4 bv[4];
    if (RELU_IN) {
        const float4* bp = reinterpret_cast<const float4*>(bias);
#pragma unroll
        for (int q = 0; q < 4; ++q) bv[q] = bp[q];
    }
    __syncthreads();
    const int s = bofs[b], e = bofs[b + 1];
    for (int k = s + (int)threadIdx.x; k < e; k += 256) {
        int2 p = pairs[k];                       // still packed (unsorted bucket)
        int col = p.x & 0xFFFFF, rl = p.x >> 20;
        float v = __int_as_float(p.y);
        const float4* xp = reinterpret_cast<const float4*>(&X[(size_t)col * HH]);
        float* ar = &acc[rl * ACCP];
#pragma unroll
        for (int q = 0; q < 4; ++q) {
            float4 x = xp[q];
            if (RELU_IN) {
                x.x = fmaxf(x.x + bv[q].x, 0.f); x.y = fmaxf(x.y + bv[q].y, 0.f);
                x.z = fmaxf(x.z + bv[q].z, 0.f); x.w = fmaxf(x.w + bv[q].w, 0.f);
            }
            atomicAdd(&ar[q * 4 + 0], v * x.x);
            atomicAdd(&ar[q * 4 + 1], v * x.y);
            atomicAdd(&ar[q * 4 + 2], v * x.z);
            atomicAdd(&ar[q * 4 + 3], v * x.w);
        }
    }
    __syncthreads();
    const int rowbase = b << BSH;
    for (int i = (int)threadIdx.x; i < BROWS * HH; i += 256) {
        int rl = i >> 4, j = i & 15, row = rowbase + rl;
        if (row < nrows) S[(size_t)row * HH + j] = acc[rl * ACCP + j];
    }
}

// ---------------------------------------------------------------------------
// Fallback scatter spmm (used only if workspace too small for bucket path).
// ---------------------------------------------------------------------------
__global__ __launch_bounds__(256) void k_spmm(const int* __restrict__ rows,
                                              const int* __restrict__ cols,
                                              const float* __restrict__ vals,
                                              const float* __restrict__ X,
                                              float* __restrict__ S,
                                              const float* __restrict__ bias,
                                              int relu_in, int nnz) {
    long long idx = (long long)blockIdx.x * 256 + threadIdx.x;
    if (idx >= (long long)nnz * HH) return;
    int e = (int)(idx >> 4);
    int j = (int)(idx & 15);
    int c = cols[e];
    int r = rows[e];
    float v = vals[e];
    float x = X[(size_t)c * HH + j];
    if (relu_in) {
        x = x + bias[j];
        x = x > 0.f ? x : 0.f;
    }
    atomicAdd(&S[(size_t)r * HH + j], v * x);
}

// ---------------------------------------------------------------------------
// K4: out = log_softmax(relu(T @ W2 + b2)).  One thread per row.
// ---------------------------------------------------------------------------
__global__ __launch_bounds__(256) void k_out(const float* __restrict__ T,
                                             const float* __restrict__ W2,
                                             const float* __restrict__ b2,
                                             float* __restrict__ out,
                                             int nrows) {
    __shared__ float w2s[HH * CC];
    __shared__ float b2s[CC];
    for (int i = (int)threadIdx.x; i < HH * CC; i += 256) w2s[i] = W2[i];
    if (threadIdx.x < CC) b2s[threadIdx.x] = b2[threadIdx.x];
    __syncthreads();

    int row = blockIdx.x * 256 + (int)threadIdx.x;
    if (row >= nrows) return;

    float t[HH];
#pragma unroll
    for (int k4 = 0; k4 < HH; k4 += 4) {
        float4 tv = *reinterpret_cast<const float4*>(&T[(size_t)row * HH + k4]);
        t[k4] = tv.x; t[k4 + 1] = tv.y; t[k4 + 2] = tv.z; t[k4 + 3] = tv.w;
    }

    float y[CC];
#pragma unroll
    for (int j = 0; j < CC; ++j) {
        float a = b2s[j];
#pragma unroll
        for (int k = 0; k < HH; ++k) a += t[k] * w2s[k * CC + j];
        y[j] = a > 0.f ? a : 0.f;
    }

    float m = y[0];
#pragma unroll
    for (int j = 1; j < CC; ++j) m = fmaxf(m, y[j]);
    float s = 0.f;
#pragma unroll
    for (int j = 0; j < CC; ++j) s += __expf(y[j] - m);
    float ls = __logf(s) + m;

    float4* op = reinterpret_cast<float4*>(&out[(size_t)row * CC]);
#pragma unroll
    for (int j4 = 0; j4 < CC / 4; ++j4)
        op[j4] = make_float4(y[j4 * 4 + 0] - ls, y[j4 * 4 + 1] - ls,
                             y[j4 * 4 + 2] - ls, y[j4 * 4 + 3] - ls);
}

// ---------------------------------------------------------------------------
// Inputs (setup_inputs order):
//  0: H      (N*512 f32)     1: A_vals (NNZ f32)   2: W1 (512*16 f32)
//  3: b1     (16 f32)        4: W2     (16*40 f32) 5: b2 (40 f32)
//  6: A_rows (NNZ i32)       7: A_cols (NNZ i32)
// Output: N*40 f32 (log_softmax)
// ---------------------------------------------------------------------------
extern "C" void kernel_launch(void* const* d_in, const int* in_sizes, int n_in,
                              void* d_out, int out_size, void* d_ws, size_t ws_size,
                              hipStream_t stream) {
    const float* Hm  = (const float*)d_in[0];
    const float* Av  = (const float*)d_in[1];
    const float* W1  = (const float*)d_in[2];
    const float* b1  = (const float*)d_in[3];
    const float* W2  = (const float*)d_in[4];
    const float* b2  = (const float*)d_in[5];
    const int*   Ar  = (const int*)d_in[6];
    const int*   Ac  = (const int*)d_in[7];
    float*       out = (float*)d_out;

    const int N    = in_sizes[0] / DD;
    const int NNZ  = in_sizes[6];
    const int NB1  = (N + BROWS - 1) >> BSH;       // buckets of 128 dest rows
    const int NBLK = (NNZ + EPB - 1) / EPB;        // edge blocks

    // Workspace layout (identical footprint to round-3's proven-fitting one)
    float* X1    = (float*)d_ws;                   // N*16
    float* S1    = X1 + (size_t)N * HH;            // N*16
    float* T     = S1 + (size_t)N * HH;            // N*16
    int*   bcnt  = (int*)(T + (size_t)N * HH);     // NB1 (reused as bflag)
    int*   bofs  = bcnt + NB1;                     // NB1+1
    int*   cnt2d = bofs + NB1 + 1;                 // NBLK*NB1 (reused as rofs)
    int2*  pairs = (int2*)((((uintptr_t)(cnt2d + (size_t)NBLK * NB1)) + 7) & ~(uintptr_t)7);

    int*   rofs  = cnt2d;                          // alias: rofs[N+1] after bscatter
    int*   bflag = bcnt;                           // alias: after bscan

    bool bucket_ok = (NB1 <= 1024) && (NBLK <= 1024) && (N < (1 << 20)) &&
                     ((size_t)NBLK * NB1 >= (size_t)(N + 2)) &&
                     (ws_size >= (size_t)((char*)(pairs + NNZ) - (char*)d_ws));

    // K1: X1 = H @ W1 (independent of bucket build)
    int g1 = (N + G1R - 1) / G1R;
    k_gemm1<<<g1, 256, 0, stream>>>(Hm, W1, X1, N);

    if (bucket_ok) {
        // Atomic-free bucket build + per-bucket counting sort -> CSR
        k_bhist   <<<NBLK, 512, 0, stream>>>(Ar, cnt2d, NNZ, NB1);
        k_colscan <<<NB1, 1024, 0, stream>>>(cnt2d, bcnt, NBLK, NB1);
        k_bscan   <<<1, 1024, 0, stream>>>(bcnt, bofs, NB1, NNZ);
        k_bscatter<<<NBLK, 512, 0, stream>>>(Ar, Ac, Av, bofs, cnt2d, pairs, NNZ, NB1);
        k_bsort   <<<NB1, 256, 0, stream>>>(bofs, pairs, rofs, bflag, N);

        // Row-gather SpMM x2: zero atomics, fully coalesced output
        int gs = (N + 63) / 64;
        k_spmm_row<0><<<gs, 256, 0, stream>>>(rofs, pairs, X1, S1, b1, N);
        k_spmm_solo<0><<<NB1, 256, 0, stream>>>(bofs, bflag, pairs, X1, S1, b1, N);
        k_spmm_row<1><<<gs, 256, 0, stream>>>(rofs, pairs, S1, T, b1, N);
        k_spmm_solo<1><<<NB1, 256, 0, stream>>>(bofs, bflag, pairs, S1, T, b1, N);
    } else {
        hipMemsetAsync(S1, 0, (size_t)2 * N * HH * sizeof(float), stream);
        long long work = (long long)NNZ * HH;
        int g2 = (int)((work + 255) / 256);
        k_spmm<<<g2, 256, 0, stream>>>(Ar, Ac, Av, X1, S1, b1, 0, NNZ);
        k_spmm<<<g2, 256, 0, stream>>>(Ar, Ac, Av, S1, T,  b1, 1, NNZ);
    }

    // K4: out = log_softmax(relu(T @ W2 + b2))
    int g4 = (N + 255) / 256;
    k_out<<<g4, 256, 0, stream>>>(T, W2, b2, out, N);
}